// Round 1
// baseline (589.556 us; speedup 1.0000x reference)
//
#include <hip/hip_runtime.h>

#define V1n 40962
#define V2n 163842
#define Bn  4

typedef _Float16 h8   __attribute__((ext_vector_type(8)));
typedef _Float16 h2   __attribute__((ext_vector_type(2)));
typedef float    f32x4 __attribute__((ext_vector_type(4)));

__device__ __forceinline__ float h2f(_Float16 h) { return (float)h; }

// ---------------- K0: pack Wup into fp16 MFMA B-fragment layout (unchanged)
__global__ __launch_bounds__(256) void k_pack_up(const float* __restrict__ Wup,
                                                 _Float16* __restrict__ WupP) {
  int i = blockIdx.x * 256 + threadIdx.x;
  if (i >= 14336) return;
  int e = i & 7, col = (i >> 3) & 15, g = i >> 7;   // g = (kt*4+quad)*14 + nt
  int nt = g % 14, kq = g / 14;
  int j = nt * 16 + col;
  int k = (kq >> 2) * 32 + (kq & 3) * 8 + e;
  WupP[i] = (_Float16)Wup[j * 64 + k];
}

// ---------------- K1: upconv GEMM, batch-fused; writes rawq interleaved (V1*7, B, 32)
__global__ __launch_bounds__(256, 4) void k_upconv(const float* __restrict__ x1,
    const float* __restrict__ bup, const _Float16* __restrict__ WupP,
    _Float16* __restrict__ rawq) {
  int lane = threadIdx.x & 63, wv = threadIdx.x >> 6;
  int col = lane & 15, quad = lane >> 4;
  int v0 = blockIdx.x * 64 + wv * 16;
  int v = v0 + col;
  int vc = min(v, V1n - 1);
  // stride 232 (not 224): spreads LDS banks for the 16B reads below (2-way max = free)
  __shared__ _Float16 tile[4][16 * 232];
  _Float16* tw = tile[wv];
  float bias[14];
#pragma unroll
  for (int nt = 0; nt < 14; ++nt) bias[nt] = bup[nt * 16 + col];
  const _Float16* wp0 = WupP + (size_t)(quad * 14) * 128 + col * 8;
  const _Float16* wp1 = WupP + (size_t)((4 + quad) * 14) * 128 + col * 8;
  int rem = V1n - v0;
  int r = lane >> 2, part = lane & 3;
  for (int b = 0; b < 4; ++b) {
    const float* xb = x1 + ((size_t)b * 64) * V1n + vc;
    h8 a0, a1;
#pragma unroll
    for (int e = 0; e < 8; ++e) a0[e] = (_Float16)xb[(size_t)(quad * 8 + e) * V1n];
#pragma unroll
    for (int e = 0; e < 8; ++e) a1[e] = (_Float16)xb[(size_t)(32 + quad * 8 + e) * V1n];
    f32x4 acc[14];
#pragma unroll
    for (int nt = 0; nt < 14; ++nt) acc[nt] = (f32x4){bias[nt], bias[nt], bias[nt], bias[nt]};
#pragma unroll
    for (int nt = 0; nt < 14; ++nt) {
      h8 bb = *(const h8*)(wp0 + nt * 128);
      acc[nt] = __builtin_amdgcn_mfma_f32_16x16x32_f16(a0, bb, acc[nt], 0, 0, 0);
    }
#pragma unroll
    for (int nt = 0; nt < 14; ++nt) {
      h8 bb = *(const h8*)(wp1 + nt * 128);
      acc[nt] = __builtin_amdgcn_mfma_f32_16x16x32_f16(a1, bb, acc[nt], 0, 0, 0);
    }
#pragma unroll
    for (int nt = 0; nt < 14; ++nt)
#pragma unroll
      for (int rr = 0; rr < 4; ++rr)
        tw[(quad * 4 + rr) * 232 + nt * 16 + col] = (_Float16)acc[nt][rr];
    __syncthreads();
    // interleaved store: element (v0+r, g*32+c) -> rawq[(((v0+r)*7+g)*4+b)*32 + c]
    if (rem >= 16) {
#pragma unroll
      for (int g = 0; g < 7; ++g)
        *(h8*)(rawq + (((size_t)(v0 + r) * 7 + g) * 4 + b) * 32 + part * 8) =
            *(const h8*)(tw + r * 232 + g * 32 + part * 8);
    } else if (rem > 0) {
      for (int g = 0; g < 7; ++g)
        if (r < rem)
          *(h8*)(rawq + (((size_t)(v0 + r) * 7 + g) * 4 + b) * 32 + part * 8) =
              *(const h8*)(tw + r * 232 + g * 32 + part * 8);
    }
  }
}

// ---------------- K2: assemble, batch-fused: thread -> (v, b); 4-lane groups read a full
// 256 B interleaved rawq region per flat index (2 lines fully used vs 4 half-used lines).
__global__ __launch_bounds__(256) void k_assemble(const float* __restrict__ x2,
    const int* __restrict__ top, const int* __restrict__ down,
    const _Float16* __restrict__ rawq, _Float16* __restrict__ y) {
  int t = blockIdx.x * 256 + threadIdx.x;
  int v = t >> 2, b = t & 3;
  if (v >= V2n) return;
  h8 r0, r1, r2, r3;
  if (v < V1n) {
    int f = top[v];
    const _Float16* src = rawq + ((size_t)f * 4 + b) * 32;
    r0 = *(const h8*)src;        r1 = *(const h8*)(src + 8);
    r2 = *(const h8*)(src + 16); r3 = *(const h8*)(src + 24);
  } else {
    int k = v - V1n;
    int d0 = down[2 * k], d1 = down[2 * k + 1];
    const _Float16* se = rawq + ((size_t)d0 * 4 + b) * 32;
    const _Float16* so = rawq + ((size_t)d1 * 4 + b) * 32;
    h8 a0 = *(const h8*)se,        a1 = *(const h8*)(se + 8);
    h8 a2 = *(const h8*)(se + 16), a3 = *(const h8*)(se + 24);
    h8 c0 = *(const h8*)so,        c1 = *(const h8*)(so + 8);
    h8 c2 = *(const h8*)(so + 16), c3 = *(const h8*)(so + 24);
#pragma unroll
    for (int i = 0; i < 4; ++i) {
      r0[i]     = (_Float16)(0.5f * (h2f(a0[2 * i]) + h2f(a0[2 * i + 1])));
      r0[4 + i] = (_Float16)(0.5f * (h2f(a1[2 * i]) + h2f(a1[2 * i + 1])));
      r1[i]     = (_Float16)(0.5f * (h2f(a2[2 * i]) + h2f(a2[2 * i + 1])));
      r1[4 + i] = (_Float16)(0.5f * (h2f(a3[2 * i]) + h2f(a3[2 * i + 1])));
      r2[i]     = (_Float16)(0.5f * (h2f(c0[2 * i]) + h2f(c0[2 * i + 1])));
      r2[4 + i] = (_Float16)(0.5f * (h2f(c1[2 * i]) + h2f(c1[2 * i + 1])));
      r3[i]     = (_Float16)(0.5f * (h2f(c2[2 * i]) + h2f(c2[2 * i + 1])));
      r3[4 + i] = (_Float16)(0.5f * (h2f(c3[2 * i]) + h2f(c3[2 * i + 1])));
    }
  }
  // y stays (B, V2, 64): conv1's rows are already exactly one 128 B line per batch
  _Float16* dst = y + ((size_t)b * V2n + v) * 64;
  *(h8*)(dst)      = r0; *(h8*)(dst + 8)  = r1;
  *(h8*)(dst + 16) = r2; *(h8*)(dst + 24) = r3;
  const float* xp = x2 + (size_t)b * 32 * V2n + v;
#pragma unroll
  for (int g2 = 0; g2 < 4; ++g2) {
    h8 px;
#pragma unroll
    for (int e = 0; e < 8; ++e) px[e] = (_Float16)xp[(size_t)(g2 * 8 + e) * V2n];
    *(h8*)(dst + 32 + g2 * 8) = px;
  }
}

// ---------------- K2b: pack W1/W2 into fp16 MFMA B-fragment layout (unchanged)
__global__ __launch_bounds__(256) void k_pack(const float* __restrict__ W1,
    const float* __restrict__ W2, _Float16* __restrict__ W1p,
    _Float16* __restrict__ W2p) {
  int i = blockIdx.x * 256 + threadIdx.x;
  if (i < 14336) {
    int e = i & 7, o = (i >> 3) & 31, g = i >> 8;       // g = kt*4+quad
    int k = (g >> 2) * 32 + (g & 3) * 8 + e;
    W1p[i] = (_Float16)W1[o * 448 + k];
  }
  int i2 = i - 14336;
  if (i2 >= 0 && i2 < 7168) {
    int e = i2 & 7, o = (i2 >> 3) & 31, g = i2 >> 8;
    int k = (g >> 2) * 32 + (g & 3) * 8 + e;
    W2p[i2] = (_Float16)W2[o * 224 + k];
  }
}

// ---------------- K3: conv1 + fused BN1-stats. Unchanged except t1 is now interleaved (V2,B,32)
__global__ __launch_bounds__(256, 4) void k_conv1(const _Float16* __restrict__ y,
    const int* __restrict__ neigh, const _Float16* __restrict__ W1p,
    _Float16* __restrict__ t1, float* __restrict__ sumsR) {
  int b = blockIdx.y;
  int lane = threadIdx.x & 63, wv = threadIdx.x >> 6;
  int col = lane & 15, quad = lane >> 4;
  int v0 = blockIdx.x * 64 + wv * 16;
  int v = v0 + col;
  int vc = min(v, V2n - 1);
  const int* np = neigh + 7 * (size_t)vc;
  int idx[7];
#pragma unroll
  for (int j = 0; j < 7; ++j) idx[j] = np[j];
  const _Float16* yb = y + (size_t)b * V2n * 64 + quad * 8;
  h8 a[14];
#pragma unroll
  for (int j = 0; j < 7; ++j) {
    const _Float16* r = yb + (size_t)idx[j] * 64;
    a[2 * j]     = *(const h8*)r;
    a[2 * j + 1] = *(const h8*)(r + 32);
  }
  f32x4 acc0 = {0.f, 0.f, 0.f, 0.f}, acc1 = {0.f, 0.f, 0.f, 0.f};
  const _Float16* wp = W1p + quad * 256;
#pragma unroll
  for (int kt = 0; kt < 14; ++kt) {
    h8 b0 = *(const h8*)(wp + (size_t)kt * 1024 + col * 8);
    h8 b1 = *(const h8*)(wp + (size_t)kt * 1024 + (16 + col) * 8);
    acc0 = __builtin_amdgcn_mfma_f32_16x16x32_f16(a[kt], b0, acc0, 0, 0, 0);
    acc1 = __builtin_amdgcn_mfma_f32_16x16x32_f16(a[kt], b1, acc1, 0, 0, 0);
  }
  __shared__ _Float16 tile[4][16][32];
  __shared__ float red[4][4][16];
#pragma unroll
  for (int r = 0; r < 4; ++r) {
    tile[wv][quad * 4 + r][col]      = (_Float16)acc0[r];
    tile[wv][quad * 4 + r][16 + col] = (_Float16)acc1[r];
  }
  __syncthreads();
  int row = threadIdx.x >> 2, ch = threadIdx.x & 3;
  int vv = blockIdx.x * 64 + row;
  float s[8], q[8];
#pragma unroll
  for (int e = 0; e < 8; ++e) { s[e] = 0.f; q[e] = 0.f; }
  if (vv < V2n) {
    h8 val = *(const h8*)&tile[row >> 4][row & 15][ch * 8];
    *(h8*)(t1 + ((size_t)vv * 4 + b) * 32 + ch * 8) = val;   // interleaved (V2,B,32)
#pragma unroll
    for (int e = 0; e < 8; ++e) { float x = h2f(val[e]); s[e] = x; q[e] = x * x; }
  }
#pragma unroll
  for (int m = 4; m <= 32; m <<= 1) {
#pragma unroll
    for (int e = 0; e < 8; ++e) { s[e] += __shfl_xor(s[e], m); q[e] += __shfl_xor(q[e], m); }
  }
  if (lane < 4) {
#pragma unroll
    for (int e = 0; e < 8; ++e) { red[wv][lane][e] = s[e]; red[wv][lane][8 + e] = q[e]; }
  }
  __syncthreads();
  if (threadIdx.x < 64) {
    int chh = threadIdx.x >> 4, e = threadIdx.x & 15;
    float v4 = red[0][chh][e] + red[1][chh][e] + red[2][chh][e] + red[3][chh][e];
    int c = chh * 8 + (e & 7);
    int rep = blockIdx.x & 63;
    float* dst = sumsR + rep * 256 + ((e < 8) ? (b * 32 + c) : (128 + b * 32 + c));
    atomicAdd(dst, v4);
  }
}

// ---------------- finalize (unchanged)
__global__ void k_finalize(const float* __restrict__ sumsR, const float* __restrict__ g,
                           const float* __restrict__ be, float* __restrict__ sc,
                           float* __restrict__ sh) {
  int i = threadIdx.x;
  if (i >= 128) return;
  float s = 0.f, q = 0.f;
  for (int r = 0; r < 64; ++r) { s += sumsR[r * 256 + i]; q += sumsR[r * 256 + 128 + i]; }
  float inv = 1.0f / (float)V2n;
  float mu = s * inv;
  float var = fmaf(q, inv, -mu * mu);
  float rs = rsqrtf(var + 1e-5f);
  int o = i & 31;
  float scale = rs * g[o];
  sc[i] = scale;
  sh[i] = fmaf(-mu, scale, be[o]);
}

// ---------------- K5: conv2, BATCH-FUSED. Reads interleaved t1 (V2,B,32): per (vertex,
// neighbor) one wave consumes a full 256 B region for all 4 batches -> 2 fully-used lines
// instead of 4 half-used ones. Writes pre-BN2 result as fp16 t2 (B,32,V2).
__global__ __launch_bounds__(256, 3) void k_conv2(const _Float16* __restrict__ t1,
    const int* __restrict__ neigh, const _Float16* __restrict__ W2p,
    const float* __restrict__ sc1, const float* __restrict__ sh1,
    _Float16* __restrict__ t2, float* __restrict__ sumsR) {
  int lane = threadIdx.x & 63, wv = threadIdx.x >> 6;
  int col = lane & 15, quad = lane >> 4;
  int v0 = blockIdx.x * 64 + wv * 16;
  int v = v0 + col;
  int vc = min(v, V2n - 1);
  const int* np = neigh + 7 * (size_t)vc;
  int idx[7];
#pragma unroll
  for (int j = 0; j < 7; ++j) idx[j] = np[j];
  float sc[4][8], sh[4][8];
#pragma unroll
  for (int b = 0; b < 4; ++b)
#pragma unroll
    for (int i = 0; i < 8; ++i) {
      sc[b][i] = sc1[b * 32 + quad * 8 + i];
      sh[b][i] = sh1[b * 32 + quad * 8 + i];
    }
  f32x4 acc[4][2];
#pragma unroll
  for (int b = 0; b < 4; ++b) {
    acc[b][0] = (f32x4){0.f, 0.f, 0.f, 0.f};
    acc[b][1] = (f32x4){0.f, 0.f, 0.f, 0.f};
  }
  const _Float16* wp = W2p + quad * 256;
#pragma unroll
  for (int j = 0; j < 7; ++j) {
    const _Float16* r = t1 + (size_t)idx[j] * 128 + quad * 8;
    h8 raws[4];
#pragma unroll
    for (int b = 0; b < 4; ++b) raws[b] = *(const h8*)(r + b * 32);
    h8 w0 = *(const h8*)(wp + (size_t)j * 1024 + col * 8);
    h8 w1 = *(const h8*)(wp + (size_t)j * 1024 + (16 + col) * 8);
#pragma unroll
    for (int b = 0; b < 4; ++b) {
      h8 aa;
#pragma unroll
      for (int e = 0; e < 8; ++e) {
        float f = fmaf(h2f(raws[b][e]), sc[b][e], sh[b][e]);
        f = fmaxf(f, 0.2f * f);
        aa[e] = (_Float16)f;
      }
      acc[b][0] = __builtin_amdgcn_mfma_f32_16x16x32_f16(aa, w0, acc[b][0], 0, 0, 0);
      acc[b][1] = __builtin_amdgcn_mfma_f32_16x16x32_f16(aa, w1, acc[b][1], 0, 0, 0);
    }
  }
  __shared__ float red2[4][16][4];
  int vrow = v0 + quad * 4;
  bool tailblk = (blockIdx.x == gridDim.x - 1);
  int rep = blockIdx.x & 63;
#pragma unroll
  for (int b = 0; b < 4; ++b) {
    if (b) __syncthreads();
    float s0 = 0.f, q0 = 0.f, s1 = 0.f, q1 = 0.f;
    _Float16* tb = t2 + (size_t)b * 32 * V2n;
    if (!tailblk) {
      _Float16* p0 = tb + (size_t)col * V2n + vrow;
      _Float16* p1 = tb + (size_t)(16 + col) * V2n + vrow;
      *(h2*)(p0)     = (h2){(_Float16)acc[b][0][0], (_Float16)acc[b][0][1]};
      *(h2*)(p0 + 2) = (h2){(_Float16)acc[b][0][2], (_Float16)acc[b][0][3]};
      *(h2*)(p1)     = (h2){(_Float16)acc[b][1][0], (_Float16)acc[b][1][1]};
      *(h2*)(p1 + 2) = (h2){(_Float16)acc[b][1][2], (_Float16)acc[b][1][3]};
#pragma unroll
      for (int rr = 0; rr < 4; ++rr) {
        s0 += acc[b][0][rr]; q0 += acc[b][0][rr] * acc[b][0][rr];
        s1 += acc[b][1][rr]; q1 += acc[b][1][rr] * acc[b][1][rr];
      }
    } else {
#pragma unroll
      for (int rr = 0; rr < 4; ++rr) {
        if (vrow + rr < V2n) {
          tb[(size_t)col * V2n + vrow + rr]        = (_Float16)acc[b][0][rr];
          tb[(size_t)(16 + col) * V2n + vrow + rr] = (_Float16)acc[b][1][rr];
          s0 += acc[b][0][rr]; q0 += acc[b][0][rr] * acc[b][0][rr];
          s1 += acc[b][1][rr]; q1 += acc[b][1][rr] * acc[b][1][rr];
        }
      }
    }
#pragma unroll
    for (int m = 16; m <= 32; m <<= 1) {
      s0 += __shfl_xor(s0, m); q0 += __shfl_xor(q0, m);
      s1 += __shfl_xor(s1, m); q1 += __shfl_xor(q1, m);
    }
    if (lane < 16) {
      red2[wv][col][0] = s0; red2[wv][col][1] = q0;
      red2[wv][col][2] = s1; red2[wv][col][3] = q1;
    }
    __syncthreads();
    if (threadIdx.x < 64) {
      int cc = threadIdx.x & 15, which = threadIdx.x >> 4;
      float v4 = red2[0][cc][which] + red2[1][cc][which] +
                 red2[2][cc][which] + red2[3][cc][which];
      int c = (which & 2) ? cc + 16 : cc;
      float* dstp = sumsR + rep * 256 + ((which & 1) ? (128 + b * 32 + c) : (b * 32 + c));
      atomicAdd(dstp, v4);
    }
  }
}

// ---------------- K7: BN2 + LeakyReLU, reads fp16 t2, writes f32 out
__global__ __launch_bounds__(256) void k_bnorm(const _Float16* __restrict__ t2,
    const float* __restrict__ sc, const float* __restrict__ sh,
    float* __restrict__ out) {
  int row = blockIdx.y, qrt = blockIdx.x;
  float scale = sc[row], shift = sh[row];
  const _Float16* p = t2 + (size_t)row * V2n;
  float* o = out + (size_t)row * V2n;
  int i0 = qrt * 20480;
  int iend = (qrt == 3) ? 81921 : i0 + 20480;
  for (int i = i0 + (int)threadIdx.x; i < iend; i += 256) {
    h2 x = *(const h2*)(p + 2 * (size_t)i);
    float a = fmaf((float)x[0], scale, shift); a = fmaxf(a, 0.2f * a);
    float b = fmaf((float)x[1], scale, shift); b = fmaxf(b, 0.2f * b);
    *(float2*)(o + 2 * (size_t)i) = make_float2(a, b);
  }
}

extern "C" void kernel_launch(void* const* d_in, const int* in_sizes, int n_in,
                              void* d_out, int out_size, void* d_ws, size_t ws_size,
                              hipStream_t stream) {
  const float* x1   = (const float*)d_in[0];
  const float* x2   = (const float*)d_in[1];
  const int*   neigh= (const int*)d_in[2];
  const int*   top  = (const int*)d_in[3];
  const int*   down = (const int*)d_in[4];
  const float* Wup  = (const float*)d_in[5];
  const float* bup  = (const float*)d_in[6];
  const float* W1   = (const float*)d_in[7];
  // d_in[8] = b1: cancels exactly in BN -> skipped
  const float* g1   = (const float*)d_in[9];
  const float* be1  = (const float*)d_in[10];
  const float* W2   = (const float*)d_in[11];
  // d_in[12] = b2: cancels in BN -> skipped
  const float* g2   = (const float*)d_in[13];
  const float* be2  = (const float*)d_in[14];
  float* out = (float*)d_out;

  char* ws = (char*)d_ws;
  _Float16* rawq = (_Float16*)ws;                         //  73,403,904 B, (V1*7, B, 32), dead after k_assemble
  _Float16* y    = (_Float16*)(ws + 73403904);            //  83,887,104 B, (B, V2, 64)
  _Float16* t1   = (_Float16*)(ws + 157291008);           //  41,943,552 B, (V2, B, 32) interleaved
  float* stats   = (float*)(ws + 199234560);              //   4 KiB (sc/sh only)
  float* sc1 = stats;        float* sh1 = stats + 128;
  float* sc2 = stats + 256;  float* sh2 = stats + 384;
  // Overlays in the rawq region (dead after k_assemble):
  _Float16* WupP = t1;                                     // 28,672 B (t1 written later by conv1)
  _Float16* W1p  = rawq;                                   // 28,672 B
  _Float16* W2p  = rawq + 14336;                           // 14,336 B
  float* sumsR1 = (float*)(ws + (1 << 20));                // 64 reps x 256 f32 = 65,536 B
  float* sumsR2 = (float*)(ws + (1 << 20) + 65536);        // 65,536 B
  _Float16* t2  = (_Float16*)(ws + (2 << 20));             // 41,943,552 B, (B, 32, V2) fp16, in dead rawq region

  k_pack_up  <<<56, 256, 0, stream>>>(Wup, WupP);
  k_upconv   <<<641,  256, 0, stream>>>(x1, bup, WupP, rawq);       // batch-fused
  k_assemble <<<2561, 256, 0, stream>>>(x2, top, down, rawq, y);    // batch-fused (v,b) mapping
  k_pack     <<<84, 256, 0, stream>>>(W1, W2, W1p, W2p);   // rawq dead from here
  hipMemsetAsync(sumsR1, 0, 131072, stream);               // zero both replica arrays
  k_conv1    <<<dim3(2561, Bn), 256, 0, stream>>>(y, neigh, W1p, t1, sumsR1);
  k_finalize <<<1, 128, 0, stream>>>(sumsR1, g1, be1, sc1, sh1);
  k_conv2    <<<2561, 256, 0, stream>>>(t1, neigh, W2p, sc1, sh1, t2, sumsR2);  // batch-fused
  k_finalize <<<1, 128, 0, stream>>>(sumsR2, g2, be2, sc2, sh2);
  k_bnorm    <<<dim3(4, 128),   256, 0, stream>>>(t2, sc2, sh2, out);
}

// Round 2
// 460.357 us; speedup vs baseline: 1.2807x; 1.2807x over previous
//
#include <hip/hip_runtime.h>

#define V1n 40962
#define V2n 163842
#define Bn  4
#define T2S 163848   // padded t2 row stride (16B-aligned rows)

typedef _Float16 h8   __attribute__((ext_vector_type(8)));
typedef _Float16 h2   __attribute__((ext_vector_type(2)));
typedef float    f32x4 __attribute__((ext_vector_type(4)));

__device__ __forceinline__ float h2f(_Float16 h) { return (float)h; }

// ---------------- K0: pack Wup into fp16 MFMA B-fragment layout (unchanged)
__global__ __launch_bounds__(256) void k_pack_up(const float* __restrict__ Wup,
                                                 _Float16* __restrict__ WupP) {
  int i = blockIdx.x * 256 + threadIdx.x;
  if (i >= 14336) return;
  int e = i & 7, col = (i >> 3) & 15, g = i >> 7;   // g = (kt*4+quad)*14 + nt
  int nt = g % 14, kq = g / 14;
  int j = nt * 16 + col;
  int k = (kq >> 2) * 32 + (kq & 3) * 8 + e;
  WupP[i] = (_Float16)Wup[j * 64 + k];
}

// ---------------- K1: upconv GEMM. Block = 16 vertices x 4 batches (one wave per batch).
// Waves deposit results into an LDS image of the interleaved rawq span for these 16
// vertices; block then streams it out as fully-coalesced 128B-line writes.
__global__ __launch_bounds__(256, 4) void k_upconv(const float* __restrict__ x1,
    const float* __restrict__ bup, const _Float16* __restrict__ WupP,
    _Float16* __restrict__ rawq) {
  int lane = threadIdx.x & 63, wv = threadIdx.x >> 6;   // wv = batch
  int col = lane & 15, quad = lane >> 4;
  int v0 = blockIdx.x * 16;
  int v = v0 + col;
  int vc = min(v, V1n - 1);
  const float* xb = x1 + ((size_t)wv * 64) * V1n + vc;
  h8 a0, a1;
#pragma unroll
  for (int e = 0; e < 8; ++e) a0[e] = (_Float16)xb[(size_t)(quad * 8 + e) * V1n];
#pragma unroll
  for (int e = 0; e < 8; ++e) a1[e] = (_Float16)xb[(size_t)(32 + quad * 8 + e) * V1n];
  f32x4 acc[14];
#pragma unroll
  for (int nt = 0; nt < 14; ++nt) {
    float bv = bup[nt * 16 + col];
    acc[nt] = (f32x4){bv, bv, bv, bv};
  }
  const _Float16* wp0 = WupP + (size_t)(quad * 14) * 128 + col * 8;
  const _Float16* wp1 = WupP + (size_t)((4 + quad) * 14) * 128 + col * 8;
#pragma unroll
  for (int nt = 0; nt < 14; ++nt) {
    h8 bb = *(const h8*)(wp0 + nt * 128);
    acc[nt] = __builtin_amdgcn_mfma_f32_16x16x32_f16(a0, bb, acc[nt], 0, 0, 0);
  }
#pragma unroll
  for (int nt = 0; nt < 14; ++nt) {
    h8 bb = *(const h8*)(wp1 + nt * 128);
    acc[nt] = __builtin_amdgcn_mfma_f32_16x16x32_f16(a1, bb, acc[nt], 0, 0, 0);
  }
  // LDS image: [16 vertices][g*128 + b*32 + c], padded 896->912 elem/row.
  // Pad makes vertex-row stride = 456 words = 8 mod 32 banks: quads hit bank
  // groups {0,8,16,24}, 16 cols span 8 banks -> 2-way max (free).
  __shared__ _Float16 lds[16 * 912];
#pragma unroll
  for (int nt = 0; nt < 14; ++nt) {
    int gofs = (nt >> 1) * 128 + wv * 32 + (nt & 1) * 16 + col;
#pragma unroll
    for (int r = 0; r < 4; ++r)
      lds[(quad * 4 + r) * 912 + gofs] = (_Float16)acc[nt][r];
  }
  __syncthreads();
  int rem = V1n - v0;
  _Float16* dst = rawq + (size_t)v0 * 896;
#pragma unroll
  for (int i = 0; i < 7; ++i) {
    int m = i * 256 + (int)threadIdx.x;   // h8-chunk index within 16-vertex span
    int vr = m / 112;                     // 112 chunks per vertex row
    int r1 = m - vr * 112;
    if (vr < rem)
      *(h8*)(dst + (size_t)m * 8) = *(const h8*)(lds + vr * 912 + r1 * 8);
  }
}

// ---------------- K2: assemble, batch-fused: thread -> (v, b); 4-lane groups read a full
// 256 B interleaved rawq region per flat index (2 lines fully used vs 4 half-used lines).
__global__ __launch_bounds__(256) void k_assemble(const float* __restrict__ x2,
    const int* __restrict__ top, const int* __restrict__ down,
    const _Float16* __restrict__ rawq, _Float16* __restrict__ y) {
  int t = blockIdx.x * 256 + threadIdx.x;
  int v = t >> 2, b = t & 3;
  if (v >= V2n) return;
  h8 r0, r1, r2, r3;
  if (v < V1n) {
    int f = top[v];
    const _Float16* src = rawq + ((size_t)f * 4 + b) * 32;
    r0 = *(const h8*)src;        r1 = *(const h8*)(src + 8);
    r2 = *(const h8*)(src + 16); r3 = *(const h8*)(src + 24);
  } else {
    int k = v - V1n;
    int d0 = down[2 * k], d1 = down[2 * k + 1];
    const _Float16* se = rawq + ((size_t)d0 * 4 + b) * 32;
    const _Float16* so = rawq + ((size_t)d1 * 4 + b) * 32;
    h8 a0 = *(const h8*)se,        a1 = *(const h8*)(se + 8);
    h8 a2 = *(const h8*)(se + 16), a3 = *(const h8*)(se + 24);
    h8 c0 = *(const h8*)so,        c1 = *(const h8*)(so + 8);
    h8 c2 = *(const h8*)(so + 16), c3 = *(const h8*)(so + 24);
#pragma unroll
    for (int i = 0; i < 4; ++i) {
      r0[i]     = (_Float16)(0.5f * (h2f(a0[2 * i]) + h2f(a0[2 * i + 1])));
      r0[4 + i] = (_Float16)(0.5f * (h2f(a1[2 * i]) + h2f(a1[2 * i + 1])));
      r1[i]     = (_Float16)(0.5f * (h2f(a2[2 * i]) + h2f(a2[2 * i + 1])));
      r1[4 + i] = (_Float16)(0.5f * (h2f(a3[2 * i]) + h2f(a3[2 * i + 1])));
      r2[i]     = (_Float16)(0.5f * (h2f(c0[2 * i]) + h2f(c0[2 * i + 1])));
      r2[4 + i] = (_Float16)(0.5f * (h2f(c1[2 * i]) + h2f(c1[2 * i + 1])));
      r3[i]     = (_Float16)(0.5f * (h2f(c2[2 * i]) + h2f(c2[2 * i + 1])));
      r3[4 + i] = (_Float16)(0.5f * (h2f(c3[2 * i]) + h2f(c3[2 * i + 1])));
    }
  }
  // y stays (B, V2, 64): conv1's rows are already exactly one 128 B line per batch
  _Float16* dst = y + ((size_t)b * V2n + v) * 64;
  *(h8*)(dst)      = r0; *(h8*)(dst + 8)  = r1;
  *(h8*)(dst + 16) = r2; *(h8*)(dst + 24) = r3;
  const float* xp = x2 + (size_t)b * 32 * V2n + v;
#pragma unroll
  for (int g2 = 0; g2 < 4; ++g2) {
    h8 px;
#pragma unroll
    for (int e = 0; e < 8; ++e) px[e] = (_Float16)xp[(size_t)(g2 * 8 + e) * V2n];
    *(h8*)(dst + 32 + g2 * 8) = px;
  }
}

// ---------------- K2b: pack W1/W2 into fp16 MFMA B-fragment layout (unchanged)
__global__ __launch_bounds__(256) void k_pack(const float* __restrict__ W1,
    const float* __restrict__ W2, _Float16* __restrict__ W1p,
    _Float16* __restrict__ W2p) {
  int i = blockIdx.x * 256 + threadIdx.x;
  if (i < 14336) {
    int e = i & 7, o = (i >> 3) & 31, g = i >> 8;       // g = kt*4+quad
    int k = (g >> 2) * 32 + (g & 3) * 8 + e;
    W1p[i] = (_Float16)W1[o * 448 + k];
  }
  int i2 = i - 14336;
  if (i2 >= 0 && i2 < 7168) {
    int e = i2 & 7, o = (i2 >> 3) & 31, g = i2 >> 8;
    int k = (g >> 2) * 32 + (g & 3) * 8 + e;
    W2p[i2] = (_Float16)W2[o * 224 + k];
  }
}

// ---------------- K3: conv1 + fused BN1-stats; t1 interleaved (V2,B,32)
__global__ __launch_bounds__(256, 4) void k_conv1(const _Float16* __restrict__ y,
    const int* __restrict__ neigh, const _Float16* __restrict__ W1p,
    _Float16* __restrict__ t1, float* __restrict__ sumsR) {
  int b = blockIdx.y;
  int lane = threadIdx.x & 63, wv = threadIdx.x >> 6;
  int col = lane & 15, quad = lane >> 4;
  int v0 = blockIdx.x * 64 + wv * 16;
  int v = v0 + col;
  int vc = min(v, V2n - 1);
  const int* np = neigh + 7 * (size_t)vc;
  int idx[7];
#pragma unroll
  for (int j = 0; j < 7; ++j) idx[j] = np[j];
  const _Float16* yb = y + (size_t)b * V2n * 64 + quad * 8;
  h8 a[14];
#pragma unroll
  for (int j = 0; j < 7; ++j) {
    const _Float16* r = yb + (size_t)idx[j] * 64;
    a[2 * j]     = *(const h8*)r;
    a[2 * j + 1] = *(const h8*)(r + 32);
  }
  f32x4 acc0 = {0.f, 0.f, 0.f, 0.f}, acc1 = {0.f, 0.f, 0.f, 0.f};
  const _Float16* wp = W1p + quad * 256;
#pragma unroll
  for (int kt = 0; kt < 14; ++kt) {
    h8 b0 = *(const h8*)(wp + (size_t)kt * 1024 + col * 8);
    h8 b1 = *(const h8*)(wp + (size_t)kt * 1024 + (16 + col) * 8);
    acc0 = __builtin_amdgcn_mfma_f32_16x16x32_f16(a[kt], b0, acc0, 0, 0, 0);
    acc1 = __builtin_amdgcn_mfma_f32_16x16x32_f16(a[kt], b1, acc1, 0, 0, 0);
  }
  __shared__ _Float16 tile[4][16][32];
  __shared__ float red[4][4][16];
#pragma unroll
  for (int r = 0; r < 4; ++r) {
    tile[wv][quad * 4 + r][col]      = (_Float16)acc0[r];
    tile[wv][quad * 4 + r][16 + col] = (_Float16)acc1[r];
  }
  __syncthreads();
  int row = threadIdx.x >> 2, ch = threadIdx.x & 3;
  int vv = blockIdx.x * 64 + row;
  float s[8], q[8];
#pragma unroll
  for (int e = 0; e < 8; ++e) { s[e] = 0.f; q[e] = 0.f; }
  if (vv < V2n) {
    h8 val = *(const h8*)&tile[row >> 4][row & 15][ch * 8];
    *(h8*)(t1 + ((size_t)vv * 4 + b) * 32 + ch * 8) = val;   // interleaved (V2,B,32)
#pragma unroll
    for (int e = 0; e < 8; ++e) { float x = h2f(val[e]); s[e] = x; q[e] = x * x; }
  }
#pragma unroll
  for (int m = 4; m <= 32; m <<= 1) {
#pragma unroll
    for (int e = 0; e < 8; ++e) { s[e] += __shfl_xor(s[e], m); q[e] += __shfl_xor(q[e], m); }
  }
  if (lane < 4) {
#pragma unroll
    for (int e = 0; e < 8; ++e) { red[wv][lane][e] = s[e]; red[wv][lane][8 + e] = q[e]; }
  }
  __syncthreads();
  if (threadIdx.x < 64) {
    int chh = threadIdx.x >> 4, e = threadIdx.x & 15;
    float v4 = red[0][chh][e] + red[1][chh][e] + red[2][chh][e] + red[3][chh][e];
    int c = chh * 8 + (e & 7);
    int rep = blockIdx.x & 63;
    float* dst = sumsR + rep * 256 + ((e < 8) ? (b * 32 + c) : (128 + b * 32 + c));
    atomicAdd(dst, v4);
  }
}

// ---------------- finalize (unchanged)
__global__ void k_finalize(const float* __restrict__ sumsR, const float* __restrict__ g,
                           const float* __restrict__ be, float* __restrict__ sc,
                           float* __restrict__ sh) {
  int i = threadIdx.x;
  if (i >= 128) return;
  float s = 0.f, q = 0.f;
  for (int r = 0; r < 64; ++r) { s += sumsR[r * 256 + i]; q += sumsR[r * 256 + 128 + i]; }
  float inv = 1.0f / (float)V2n;
  float mu = s * inv;
  float var = fmaf(q, inv, -mu * mu);
  float rs = rsqrtf(var + 1e-5f);
  int o = i & 31;
  float scale = rs * g[o];
  sc[i] = scale;
  sh[i] = fmaf(-mu, scale, be[o]);
}

// ---------------- K5: conv2, batch-fused; reads interleaved t1; writes fp16 t2 (B,32,T2S)
__global__ __launch_bounds__(256, 3) void k_conv2(const _Float16* __restrict__ t1,
    const int* __restrict__ neigh, const _Float16* __restrict__ W2p,
    const float* __restrict__ sc1, const float* __restrict__ sh1,
    _Float16* __restrict__ t2, float* __restrict__ sumsR) {
  int lane = threadIdx.x & 63, wv = threadIdx.x >> 6;
  int col = lane & 15, quad = lane >> 4;
  int v0 = blockIdx.x * 64 + wv * 16;
  int v = v0 + col;
  int vc = min(v, V2n - 1);
  const int* np = neigh + 7 * (size_t)vc;
  int idx[7];
#pragma unroll
  for (int j = 0; j < 7; ++j) idx[j] = np[j];
  float sc[4][8], sh[4][8];
#pragma unroll
  for (int b = 0; b < 4; ++b)
#pragma unroll
    for (int i = 0; i < 8; ++i) {
      sc[b][i] = sc1[b * 32 + quad * 8 + i];
      sh[b][i] = sh1[b * 32 + quad * 8 + i];
    }
  f32x4 acc[4][2];
#pragma unroll
  for (int b = 0; b < 4; ++b) {
    acc[b][0] = (f32x4){0.f, 0.f, 0.f, 0.f};
    acc[b][1] = (f32x4){0.f, 0.f, 0.f, 0.f};
  }
  const _Float16* wp = W2p + quad * 256;
#pragma unroll
  for (int j = 0; j < 7; ++j) {
    const _Float16* r = t1 + (size_t)idx[j] * 128 + quad * 8;
    h8 raws[4];
#pragma unroll
    for (int b = 0; b < 4; ++b) raws[b] = *(const h8*)(r + b * 32);
    h8 w0 = *(const h8*)(wp + (size_t)j * 1024 + col * 8);
    h8 w1 = *(const h8*)(wp + (size_t)j * 1024 + (16 + col) * 8);
#pragma unroll
    for (int b = 0; b < 4; ++b) {
      h8 aa;
#pragma unroll
      for (int e = 0; e < 8; ++e) {
        float f = fmaf(h2f(raws[b][e]), sc[b][e], sh[b][e]);
        f = fmaxf(f, 0.2f * f);
        aa[e] = (_Float16)f;
      }
      acc[b][0] = __builtin_amdgcn_mfma_f32_16x16x32_f16(aa, w0, acc[b][0], 0, 0, 0);
      acc[b][1] = __builtin_amdgcn_mfma_f32_16x16x32_f16(aa, w1, acc[b][1], 0, 0, 0);
    }
  }
  __shared__ float red2[4][16][4];
  int vrow = v0 + quad * 4;
  bool tailblk = (blockIdx.x == gridDim.x - 1);
  int rep = blockIdx.x & 63;
#pragma unroll
  for (int b = 0; b < 4; ++b) {
    if (b) __syncthreads();
    float s0 = 0.f, q0 = 0.f, s1 = 0.f, q1 = 0.f;
    _Float16* tb = t2 + (size_t)b * 32 * T2S;
    if (!tailblk) {
      _Float16* p0 = tb + (size_t)col * T2S + vrow;
      _Float16* p1 = tb + (size_t)(16 + col) * T2S + vrow;
      *(h2*)(p0)     = (h2){(_Float16)acc[b][0][0], (_Float16)acc[b][0][1]};
      *(h2*)(p0 + 2) = (h2){(_Float16)acc[b][0][2], (_Float16)acc[b][0][3]};
      *(h2*)(p1)     = (h2){(_Float16)acc[b][1][0], (_Float16)acc[b][1][1]};
      *(h2*)(p1 + 2) = (h2){(_Float16)acc[b][1][2], (_Float16)acc[b][1][3]};
#pragma unroll
      for (int rr = 0; rr < 4; ++rr) {
        s0 += acc[b][0][rr]; q0 += acc[b][0][rr] * acc[b][0][rr];
        s1 += acc[b][1][rr]; q1 += acc[b][1][rr] * acc[b][1][rr];
      }
    } else {
#pragma unroll
      for (int rr = 0; rr < 4; ++rr) {
        if (vrow + rr < V2n) {
          tb[(size_t)col * T2S + vrow + rr]        = (_Float16)acc[b][0][rr];
          tb[(size_t)(16 + col) * T2S + vrow + rr] = (_Float16)acc[b][1][rr];
          s0 += acc[b][0][rr]; q0 += acc[b][0][rr] * acc[b][0][rr];
          s1 += acc[b][1][rr]; q1 += acc[b][1][rr] * acc[b][1][rr];
        }
      }
    }
#pragma unroll
    for (int m = 16; m <= 32; m <<= 1) {
      s0 += __shfl_xor(s0, m); q0 += __shfl_xor(q0, m);
      s1 += __shfl_xor(s1, m); q1 += __shfl_xor(q1, m);
    }
    if (lane < 16) {
      red2[wv][col][0] = s0; red2[wv][col][1] = q0;
      red2[wv][col][2] = s1; red2[wv][col][3] = q1;
    }
    __syncthreads();
    if (threadIdx.x < 64) {
      int cc = threadIdx.x & 15, which = threadIdx.x >> 4;
      float v4 = red2[0][cc][which] + red2[1][cc][which] +
                 red2[2][cc][which] + red2[3][cc][which];
      int c = (which & 2) ? cc + 16 : cc;
      float* dstp = sumsR + rep * 256 + ((which & 1) ? (128 + b * 32 + c) : (b * 32 + c));
      atomicAdd(dstp, v4);
    }
  }
}

// ---------------- K7: BN2 + LeakyReLU, vectorized: h8 (16B) reads, 4x float2 writes
__global__ __launch_bounds__(256) void k_bnorm(const _Float16* __restrict__ t2,
    const float* __restrict__ sc, const float* __restrict__ sh,
    float* __restrict__ out) {
  int row = blockIdx.y, qrt = blockIdx.x;
  float scale = sc[row], shift = sh[row];
  const _Float16* p = t2 + (size_t)row * T2S;
  float* o = out + (size_t)row * V2n;
  int c0 = qrt * 5120;   // 20480 full h8 chunks over 4 quarters
  for (int cch = c0 + (int)threadIdx.x; cch < c0 + 5120; cch += 256) {
    h8 x = *(const h8*)(p + (size_t)cch * 8);
    float* ob = o + (size_t)cch * 8;
    float f0, f1;
#pragma unroll
    for (int e = 0; e < 4; ++e) {
      f0 = fmaf((float)x[2 * e], scale, shift);     f0 = fmaxf(f0, 0.2f * f0);
      f1 = fmaf((float)x[2 * e + 1], scale, shift); f1 = fmaxf(f1, 0.2f * f1);
      *(float2*)(ob + 2 * e) = make_float2(f0, f1);
    }
  }
  if (qrt == 3 && threadIdx.x < 2) {   // 163842 = 20480*8 + 2 tail
    int i = 163840 + (int)threadIdx.x;
    float a = fmaf((float)p[i], scale, shift);
    o[i] = fmaxf(a, 0.2f * a);
  }
}

extern "C" void kernel_launch(void* const* d_in, const int* in_sizes, int n_in,
                              void* d_out, int out_size, void* d_ws, size_t ws_size,
                              hipStream_t stream) {
  const float* x1   = (const float*)d_in[0];
  const float* x2   = (const float*)d_in[1];
  const int*   neigh= (const int*)d_in[2];
  const int*   top  = (const int*)d_in[3];
  const int*   down = (const int*)d_in[4];
  const float* Wup  = (const float*)d_in[5];
  const float* bup  = (const float*)d_in[6];
  const float* W1   = (const float*)d_in[7];
  // d_in[8] = b1: cancels exactly in BN -> skipped
  const float* g1   = (const float*)d_in[9];
  const float* be1  = (const float*)d_in[10];
  const float* W2   = (const float*)d_in[11];
  // d_in[12] = b2: cancels in BN -> skipped
  const float* g2   = (const float*)d_in[13];
  const float* be2  = (const float*)d_in[14];
  float* out = (float*)d_out;

  char* ws = (char*)d_ws;
  _Float16* rawq = (_Float16*)ws;                         //  73,403,904 B, (V1*7, B, 32), dead after k_assemble
  _Float16* y    = (_Float16*)(ws + 73403904);            //  83,887,104 B, (B, V2, 64)
  _Float16* t1   = (_Float16*)(ws + 157291008);           //  41,943,552 B, (V2, B, 32) interleaved
  float* stats   = (float*)(ws + 199234560);              //   4 KiB (sc/sh only)
  float* sc1 = stats;        float* sh1 = stats + 128;
  float* sc2 = stats + 256;  float* sh2 = stats + 384;
  // Overlays in the rawq region (dead after k_assemble):
  _Float16* WupP = t1;                                     // 28,672 B (t1 written later by conv1)
  _Float16* W1p  = rawq;                                   // 28,672 B
  _Float16* W2p  = rawq + 14336;                           // 14,336 B
  float* sumsR1 = (float*)(ws + (1 << 20));                // 64 reps x 256 f32 = 65,536 B
  float* sumsR2 = (float*)(ws + (1 << 20) + 65536);        // 65,536 B
  _Float16* t2  = (_Float16*)(ws + (2 << 20));             // 41,945,088 B, (B, 32, T2S) fp16, in dead rawq region

  k_pack_up  <<<56, 256, 0, stream>>>(Wup, WupP);
  k_upconv   <<<2561, 256, 0, stream>>>(x1, bup, WupP, rawq);       // 16 vertices x 4 batches/block
  k_assemble <<<2561, 256, 0, stream>>>(x2, top, down, rawq, y);    // batch-fused (v,b) mapping
  k_pack     <<<84, 256, 0, stream>>>(W1, W2, W1p, W2p);   // rawq dead from here
  hipMemsetAsync(sumsR1, 0, 131072, stream);               // zero both replica arrays
  k_conv1    <<<dim3(2561, Bn), 256, 0, stream>>>(y, neigh, W1p, t1, sumsR1);
  k_finalize <<<1, 128, 0, stream>>>(sumsR1, g1, be1, sc1, sh1);
  k_conv2    <<<2561, 256, 0, stream>>>(t1, neigh, W2p, sc1, sh1, t2, sumsR2);  // batch-fused
  k_finalize <<<1, 128, 0, stream>>>(sumsR2, g2, be2, sc2, sh2);
  k_bnorm    <<<dim3(4, 128),   256, 0, stream>>>(t2, sc2, sh2, out);
}